// Round 10
// baseline (744.841 us; speedup 1.0000x reference)
//
#include <hip/hip_runtime.h>
#include <cstdint>

#define KU 256
#define NBASK 64
#define MBS 20
#define BITEMS 1280
#define HD 256
#define G3 768
#define TT 64

typedef short v8s __attribute__((ext_vector_type(8)));
typedef float v4f __attribute__((ext_vector_type(4)));
typedef unsigned short v4us __attribute__((ext_vector_type(4)));
typedef unsigned int v4u __attribute__((ext_vector_type(4)));

__device__ __forceinline__ unsigned short f2b(float f){
  uint32_t u = __float_as_uint(f);
  u += 0x7FFFu + ((u >> 16) & 1u);
  return (unsigned short)(u >> 16);
}
__device__ __forceinline__ float b2f(unsigned short s){
  return __uint_as_float(((uint32_t)s) << 16);
}
__device__ __forceinline__ unsigned int packf(float x){
  unsigned short hi = f2b(x);
  unsigned short lo = f2b(x - b2f(hi));
  return ((unsigned int)hi << 16) | lo;
}
__device__ __forceinline__ float unpackf(unsigned int v){
  return b2f((unsigned short)(v >> 16)) + b2f((unsigned short)(v & 0xffffu));
}
// relaxed wait: no acquire fence -> no per-step L1/L2 invalidate. The atomic
// load executes at the device coherence point, so it sees the release store.
__device__ __forceinline__ void waitflag(int* f, int v){
  while (__hip_atomic_load(f, __ATOMIC_RELAXED, __HIP_MEMORY_SCOPE_AGENT) < v)
    __builtin_amdgcn_s_sleep(2);
  asm volatile("" ::: "memory");   // keep subsequent loads below the spin
}
__device__ __forceinline__ unsigned int aload(const unsigned int* p){
  return __hip_atomic_load(p, __ATOMIC_RELAXED, __HIP_MEMORY_SCOPE_AGENT);
}

// ---------------- weight conversion: fp32 -> bf16 hi + residual lo ---------
__global__ __launch_bounds__(1024) void k_convert(
    const float* __restrict__ wih, const float* __restrict__ whh,
    unsigned short* __restrict__ wih1hi, unsigned short* __restrict__ wih1lo,
    unsigned short* __restrict__ wih2hi, unsigned short* __restrict__ wih2lo,
    unsigned short* __restrict__ whh1hi, unsigned short* __restrict__ whh1lo,
    unsigned short* __restrict__ whh2hi, unsigned short* __restrict__ whh2lo)
{
  int idx = blockIdx.x * 1024 + threadIdx.x;     // 0..196607
  int which = blockIdx.y;
  float v;
  if (which == 0)      v = wih[idx];
  else if (which == 1) v = wih[196608 + idx];
  else if (which == 2) v = whh[idx];
  else                 v = whh[196608 + idx];
  unsigned short hi = f2b(v);
  unsigned short lo = f2b(v - b2f(hi));
  if (which == 0)      { wih1hi[idx] = hi; wih1lo[idx] = lo; }
  else if (which == 1) { wih2hi[idx] = hi; wih2lo[idx] = lo; }
  else if (which == 2) { whh1hi[idx] = hi; whh1lo[idx] = lo; }
  else                 { whh2hi[idx] = hi; whh2lo[idx] = lo; }
}

// ---------------- flag init ------------------------------------------------
__global__ void k_zero(int* flags){
  if (threadIdx.x < 96) flags[threadIdx.x] = 0;
}

// ---------------- per-user basket ordering (stable: valid first) -----------
__global__ __launch_bounds__(64) void k_order(
    const float* __restrict__ prob, const int* __restrict__ seq,
    int* __restrict__ order, int* __restrict__ lengths)
{
  int k = blockIdx.x, j = threadIdx.x;           // j = basket
  int base = k * BITEMS + j * MBS;
  float mx = 0.f;
  #pragma unroll
  for (int m = 0; m < MBS; m++) {
    int it = seq[base + m];
    float p = (it >= 0) ? prob[base + m] : 0.f;
    mx = fmaxf(mx, p);
  }
  bool valid = mx > 0.f;
  unsigned long long bal = __ballot(valid);
  int len = __popcll(bal);
  unsigned long long below = bal & ((1ull << j) - 1ull);
  int pos = valid ? __popcll(below) : (len + (j - __popcll(below)));
  order[k * NBASK + j] = pos;
  if (j == 0) lengths[k] = (len > 0) ? len : 1;
}

// ---------------- basket pooling -> ordered x (bf16 hi+lo) -----------------
__global__ __launch_bounds__(256) void k_basket(
    const float* __restrict__ prob, const int* __restrict__ seq,
    const float* __restrict__ table, const int* __restrict__ order,
    unsigned short* __restrict__ xbhi, unsigned short* __restrict__ xblo)
{
  int j = blockIdx.x, k = blockIdx.y;
  int h = threadIdx.x;
  int base = k * BITEMS + j * MBS;
  float acc = 0.f, sp = 0.f;
  #pragma unroll
  for (int m = 0; m < MBS; m++) {
    int it = seq[base + m];
    if (it >= 0) {
      float p = prob[base + m];
      sp += p;
      acc += p * table[(size_t)(it + 1) * HD + h];
    }
  }
  float val = acc / (sp + 1e-10f);
  int dest = order[k * NBASK + j];
  unsigned short hi = f2b(val);
  size_t o = ((size_t)k * NBASK + dest) * HD + h;
  xbhi[o] = hi;
  xblo[o] = f2b(val - b2f(hi));
}

// ---------------- 3-product split-bf16 GEMM: Y = X @ W^T + bias ------------
__global__ __launch_bounds__(256) void k_gemm3(
    const unsigned short* __restrict__ Xhi, const unsigned short* __restrict__ Xlo,
    const unsigned short* __restrict__ Whi, const unsigned short* __restrict__ Wlo,
    const float* __restrict__ bias, float* __restrict__ Y)
{
  int nblk = blockIdx.x;              // 0..11
  int mblk = blockIdx.y;              // 0..255
  int wv = threadIdx.x >> 6;
  int l = threadIdx.x & 63;
  int r = l & 15, g = l >> 4;
  int mbase = mblk * 64 + wv * 16;
  int nbase = nblk * 64;
  v4f acc[4];
  #pragma unroll
  for (int c = 0; c < 4; c++) {
    float bn = bias[nbase + c * 16 + r];
    acc[c] = (v4f){bn, bn, bn, bn};
  }
  const unsigned short* xh = Xhi + (size_t)(mbase + r) * HD;
  const unsigned short* xl = Xlo + (size_t)(mbase + r) * HD;
  #pragma unroll
  for (int k0 = 0; k0 < HD; k0 += 32) {
    v8s ahi = *(const v8s*)(xh + k0 + g * 8);
    v8s alo = *(const v8s*)(xl + k0 + g * 8);
    #pragma unroll
    for (int c = 0; c < 4; c++) {
      size_t wo = (size_t)(nbase + c * 16 + r) * HD + k0 + g * 8;
      v8s bhi = *(const v8s*)(Whi + wo);
      v8s blo = *(const v8s*)(Wlo + wo);
      acc[c] = __builtin_amdgcn_mfma_f32_16x16x32_bf16(ahi, bhi, acc[c], 0, 0, 0);
      acc[c] = __builtin_amdgcn_mfma_f32_16x16x32_bf16(alo, bhi, acc[c], 0, 0, 0);
      acc[c] = __builtin_amdgcn_mfma_f32_16x16x32_bf16(ahi, blo, acc[c], 0, 0, 0);
    }
  }
  #pragma unroll
  for (int c = 0; c < 4; c++) {
    int n = nbase + c * 16 + r;
    int mrow = mbase + g * 4;
    #pragma unroll
    for (int i = 0; i < 4; i++)
      Y[(size_t)(mrow + i) * G3 + n] = acc[c][i];
  }
}

// ---------------- MFMA quad (4 K-slices, rolling depth-3 weight stream) ----
__device__ __forceinline__ void wprologue(
    const unsigned short* w0, const unsigned short* w1, const unsigned short* w2,
    int half4, v8s (&cw0)[3], v8s (&cw1)[3], v8s (&cw2)[3])
{
  #pragma unroll
  for (int q = 0; q < 3; q++) {
    int p = (half4 + q) & 7;
    cw0[q] = *(const v8s*)(w0 + p * 32);
    cw1[q] = *(const v8s*)(w1 + p * 32);
    cw2[q] = *(const v8s*)(w2 + p * 32);
  }
}
template<int K0>
__device__ __forceinline__ void mfma_quad(
    const unsigned short* __restrict__ w0, const unsigned short* __restrict__ w1,
    const unsigned short* __restrict__ w2,
    const unsigned short (*h_hi)[256], const unsigned short (*h_lo)[256],
    const unsigned short* __restrict__ nlo_s, int r, int g, int jloc, int half4,
    v8s (&cw0)[3], v8s (&cw1)[3], v8s (&cw2)[3],
    v4f& a0, v4f& a1, v4f& a2)
{
  #pragma unroll
  for (int q = 0; q < 4; q++) {
    int kidx = K0 + q;
    int buf = kidx % 3;                          // static after unroll
    int p = (half4 + kidx) & 7;
    int slotA = ((p * 4 + g) ^ (r & 7)) * 8;
    v8s ahi = *(const v8s*)&h_hi[r][slotA];
    v8s alo = *(const v8s*)&h_lo[r][slotA];
    v8s nl  = *(const v8s*)&nlo_s[jloc * 256 + slotA];
    v8s u0 = cw0[buf], u1 = cw1[buf], u2 = cw2[buf];
    if (kidx + 3 < 8) {
      int p3 = (half4 + kidx + 3) & 7;
      cw0[buf] = *(const v8s*)(w0 + p3 * 32);
      cw1[buf] = *(const v8s*)(w1 + p3 * 32);
      cw2[buf] = *(const v8s*)(w2 + p3 * 32);
    }
    a0 = __builtin_amdgcn_mfma_f32_16x16x32_bf16(ahi, u0, a0, 0, 0, 0);
    a0 = __builtin_amdgcn_mfma_f32_16x16x32_bf16(alo, u0, a0, 0, 0, 0);
    a1 = __builtin_amdgcn_mfma_f32_16x16x32_bf16(ahi, u1, a1, 0, 0, 0);
    a1 = __builtin_amdgcn_mfma_f32_16x16x32_bf16(alo, u1, a1, 0, 0, 0);
    a2 = __builtin_amdgcn_mfma_f32_16x16x32_bf16(ahi, u2, a2, 0, 0, 0);
    a2 = __builtin_amdgcn_mfma_f32_16x16x32_bf16(alo, u2, a2, 0, 0, 0);
    a2 = __builtin_amdgcn_mfma_f32_16x16x32_bf16(ahi, nl, a2, 0, 0, 0);
  }
}

// ---- stage-A gi prefetch: 16 users x own j-half (3x128 cols) -> LDS -------
// 48 rows x 32 v4f = 1536 items / 512 threads = 3 each, coalesced per row.
__device__ __forceinline__ void load_gi(
    const float* __restrict__ gi, int ub, int t, int half, int tid,
    float (*gs)[388])
{
  v4f tmp[3];
  #pragma unroll
  for (int k = 0; k < 3; k++) {
    int idx = k * 512 + tid;
    int row = idx >> 5, c4 = idx & 31;
    int u = row / 3, gate = row - u * 3;
    tmp[k] = *(const v4f*)(gi + ((size_t)(ub + u) * TT + t) * G3
                              + gate * 256 + half * 128 + c4 * 4);
  }
  #pragma unroll
  for (int k = 0; k < 3; k++) {
    int idx = k * 512 + tid;
    int row = idx >> 5, c4 = idx & 31;
    int u = row / 3, gate = row - u * 3;
    *(v4f*)&gs[u][gate * 128 + c4 * 4] = tmp[k];
  }
}

// ---------------- j-split 3-stage pipelined GRU (96 blocks x 512) ----------
// Topology as round 9. Sync changes: producers RELEASE only (no threadfence);
// consumers RELAXED (no L1/L2 invalidate -> weight stream stays L2-warm).
// Reused-address buffers (h2x, packed gi2) read via relaxed AGENT atomics
// (coherence-point reads, stale-cache-proof). Stage A's gi(t) comes from an
// LDS double buffer filled one step ahead -> HBM never poisons weight waits.
__global__ __launch_bounds__(512) void k_pipe(
    const unsigned short* __restrict__ whh1hi, const unsigned short* __restrict__ whh1lo,
    const unsigned short* __restrict__ wih2hi, const unsigned short* __restrict__ wih2lo,
    const unsigned short* __restrict__ whh2hi, const unsigned short* __restrict__ whh2lo,
    float* __restrict__ gi, unsigned int* __restrict__ h1pk, unsigned int* __restrict__ h2x,
    const float* __restrict__ bhh1, const float* __restrict__ bih2,
    const float* __restrict__ bhh2,
    const int* __restrict__ lengths, float* __restrict__ out, int* flags)
{
  __shared__ unsigned short h_hi[16][256], h_lo[16][256];  // 16 KB
  __shared__ unsigned short nlo_s[32768];                  // 64 KB
  __shared__ float gi_s[2][16][388];                       // 48.5 KB (A only)
  int tid = threadIdx.x;
  int l = tid & 63, r = l & 15, g = l >> 4;
  int swv = __builtin_amdgcn_readfirstlane(tid >> 6);
  int bx = blockIdx.x;
  int role = bx >> 5, sub = bx & 31, half = sub >> 4, b = sub & 15;
  int half4 = half * 4;
  int ub = b * 16;
  int jloc = swv * 16 + r, j = half * 128 + jloc;
  int* aflag = flags, *gflag = flags + 32, *bflag = flags + 64;
  int myf = sub, sibf = sub ^ 16;

  const unsigned short* whi_g = (role == 0) ? whh1hi : (role == 1) ? wih2hi : whh2hi;
  const unsigned short* wlo_g = (role == 0) ? whh1lo : (role == 1) ? wih2lo : whh2lo;
  const float* bb_ = (role == 0) ? bhh1 : (role == 1) ? bih2 : bhh2;

  for (int idx = tid; idx < 4096; idx += 512) {
    ((unsigned short*)h_hi)[idx] = 0;
    ((unsigned short*)h_lo)[idx] = 0;
  }
  // stage this block's n-gate lo rows (its j-half), MFMA-read swizzled
  const unsigned short* wlo_n = wlo_g + 2 * 65536 + half * 128 * 256;
  for (int idx = tid; idx < 32768; idx += 512) {
    int row = idx >> 8, col = idx & 255;
    int slot = (col >> 3) ^ (row & 7);
    nlo_s[row * 256 + slot * 8 + (col & 7)] = wlo_n[idx];
  }
  const unsigned short* w0 = whi_g + (size_t)j * 256 + g * 8;
  const unsigned short* w1 = w0 + 65536;
  const unsigned short* w2 = w0 + 131072;
  float b_r = bb_[j], b_z = bb_[256 + j], b_n = bb_[512 + j];
  int sibbase = (1 - half) * 128;
  int xu = tid >> 5;                           // exchange helper coords
  __syncthreads();

  if (role == 0) {
    // ===== stage A: layer-1 recurrence (j-half) =====
    float hold[4] = {0.f, 0.f, 0.f, 0.f};
    unsigned int* hq[4];
    #pragma unroll
    for (int i = 0; i < 4; i++)
      hq[i] = h1pk + (size_t)(ub + g * 4 + i) * TT * HD + j;
    load_gi(gi, ub, 0, half, tid, gi_s[0]);
    __syncthreads();
    for (int t = 0; t < TT; t++) {
      v8s cw0[3], cw1[3], cw2[3];
      wprologue(w0, w1, w2, half4, cw0, cw1, cw2);
      v4f a0 = {0.f,0.f,0.f,0.f}, a1 = {0.f,0.f,0.f,0.f}, a2 = {0.f,0.f,0.f,0.f};
      mfma_quad<0>(w0, w1, w2, h_hi, h_lo, nlo_s, r, g, jloc, half4, cw0, cw1, cw2, a0, a1, a2);
      if (t > 0 && tid == 0) waitflag(&aflag[sibf], t);
      __syncthreads();
      if (t > 0) {
        int sj = sibbase + (tid & 31) * 4;
        v4u pk = *(const v4u*)&h1pk[((size_t)(ub + xu) * TT + (t - 1)) * HD + sj];
        int pos = (((sj >> 3) ^ (xu & 7)) << 3) + (sj & 7);
        v4us hv, lv;
        #pragma unroll
        for (int i = 0; i < 4; i++) { hv[i] = (unsigned short)(pk[i] >> 16); lv[i] = (unsigned short)(pk[i] & 0xffffu); }
        *(v4us*)&h_hi[xu][pos] = hv;
        *(v4us*)&h_lo[xu][pos] = lv;
      }
      __syncthreads();
      mfma_quad<4>(w0, w1, w2, h_hi, h_lo, nlo_s, r, g, jloc, half4, cw0, cw1, cw2, a0, a1, a2);
      if (t + 1 < TT) load_gi(gi, ub, t + 1, half, tid, gi_s[(t + 1) & 1]);
      #pragma unroll
      for (int i = 0; i < 4; i++) {
        int u = g * 4 + i;
        float ir  = gi_s[t & 1][u][jloc];
        float iz  = gi_s[t & 1][u][128 + jloc];
        float inn = gi_s[t & 1][u][256 + jloc];
        float hr = a0[i] + b_r, hz = a1[i] + b_z, hn = a2[i] + b_n;
        float rr = 1.f / (1.f + __expf(-(ir + hr)));
        float zz = 1.f / (1.f + __expf(-(iz + hz)));
        float e  = __expf(2.f * (inn + rr * hn));
        float nn = 1.f - 2.f / (e + 1.f);
        float hnew = (1.f - zz) * nn + zz * hold[i];
        hold[i] = hnew;
        unsigned short h_  = f2b(hnew);
        unsigned short lo_ = f2b(hnew - b2f(h_));
        int pos = (((j >> 3) ^ (u & 7)) << 3) + (j & 7);
        h_hi[u][pos] = h_;
        h_lo[u][pos] = lo_;
        hq[i][0] = ((unsigned int)h_ << 16) | lo_;
        hq[i] += HD;
      }
      __syncthreads();
      if (tid == 0)
        __hip_atomic_store(&aflag[myf], t + 1, __ATOMIC_RELEASE, __HIP_MEMORY_SCOPE_AGENT);
    }
  } else if (role == 1) {
    // ===== stage G: gi2(t) = h1(t) @ wih2^T + bih2 (j-half rows) =====
    unsigned int* gi_u = (unsigned int*)gi;
    for (int t = 0; t < TT; t++) {
      if (tid == 0) { waitflag(&aflag[b], t + 1); waitflag(&aflag[16 + b], t + 1); }
      __syncthreads();
      {
        int c0 = (tid & 31) * 8;
        const unsigned int* src = &h1pk[((size_t)(ub + xu) * TT + t) * HD + c0];
        #pragma unroll
        for (int hf = 0; hf < 2; hf++) {
          v4u pk = *(const v4u*)(src + hf * 4);
          int sj = c0 + hf * 4;
          int pos = (((sj >> 3) ^ (xu & 7)) << 3) + (sj & 7);
          v4us hv, lv;
          #pragma unroll
          for (int i = 0; i < 4; i++) { hv[i] = (unsigned short)(pk[i] >> 16); lv[i] = (unsigned short)(pk[i] & 0xffffu); }
          *(v4us*)&h_hi[xu][pos] = hv;
          *(v4us*)&h_lo[xu][pos] = lv;
        }
      }
      __syncthreads();
      v8s cw0[3], cw1[3], cw2[3];
      wprologue(w0, w1, w2, half4, cw0, cw1, cw2);
      v4f a0 = {b_r, b_r, b_r, b_r}, a1 = {b_z, b_z, b_z, b_z}, a2 = {b_n, b_n, b_n, b_n};
      mfma_quad<0>(w0, w1, w2, h_hi, h_lo, nlo_s, r, g, jloc, half4, cw0, cw1, cw2, a0, a1, a2);
      mfma_quad<4>(w0, w1, w2, h_hi, h_lo, nlo_s, r, g, jloc, half4, cw0, cw1, cw2, a0, a1, a2);
      #pragma unroll
      for (int i = 0; i < 4; i++) {
        size_t base = ((size_t)(ub + g * 4 + i) * TT + t) * G3;
        gi_u[base + j]       = packf(a0[i]);
        gi_u[base + 256 + j] = packf(a1[i]);
        gi_u[base + 512 + j] = packf(a2[i]);
      }
      __syncthreads();
      if (tid == 0)
        __hip_atomic_store(&gflag[myf], t + 1, __ATOMIC_RELEASE, __HIP_MEMORY_SCOPE_AGENT);
    }
  } else {
    // ===== stage B: layer-2 recurrence (j-half) =====
    float hold[4] = {0.f, 0.f, 0.f, 0.f};
    const unsigned int* gq[4];
    int lenr[4];
    #pragma unroll
    for (int i = 0; i < 4; i++) {
      gq[i] = (const unsigned int*)gi + (size_t)(ub + g * 4 + i) * TT * G3 + j;
      lenr[i] = lengths[ub + g * 4 + i];
    }
    for (int t = 0; t < TT; t++) {
      v8s cw0[3], cw1[3], cw2[3];
      wprologue(w0, w1, w2, half4, cw0, cw1, cw2);
      v4f a0 = {0.f,0.f,0.f,0.f}, a1 = {0.f,0.f,0.f,0.f}, a2 = {0.f,0.f,0.f,0.f};
      mfma_quad<0>(w0, w1, w2, h_hi, h_lo, nlo_s, r, g, jloc, half4, cw0, cw1, cw2, a0, a1, a2);
      if (tid == 0) {
        waitflag(&gflag[myf], t + 1);
        if (t > 0) waitflag(&bflag[sibf], t);
      }
      __syncthreads();
      if (t > 0) {
        int sj = sibbase + (tid & 31) * 4;
        const unsigned int* hx = &h2x[(size_t)(ub + xu) * HD + sj];
        unsigned int p0 = aload(hx), p1 = aload(hx + 1), p2 = aload(hx + 2), p3 = aload(hx + 3);
        int pos = (((sj >> 3) ^ (xu & 7)) << 3) + (sj & 7);
        v4us hv, lv;
        hv[0]=(unsigned short)(p0>>16); lv[0]=(unsigned short)(p0&0xffffu);
        hv[1]=(unsigned short)(p1>>16); lv[1]=(unsigned short)(p1&0xffffu);
        hv[2]=(unsigned short)(p2>>16); lv[2]=(unsigned short)(p2&0xffffu);
        hv[3]=(unsigned short)(p3>>16); lv[3]=(unsigned short)(p3&0xffffu);
        *(v4us*)&h_hi[xu][pos] = hv;
        *(v4us*)&h_lo[xu][pos] = lv;
      }
      unsigned int vr[4], vz[4], vn[4];
      #pragma unroll
      for (int i = 0; i < 4; i++) {
        vr[i] = aload(gq[i]); vz[i] = aload(gq[i] + 256); vn[i] = aload(gq[i] + 512);
        gq[i] += G3;
      }
      __syncthreads();
      mfma_quad<4>(w0, w1, w2, h_hi, h_lo, nlo_s, r, g, jloc, half4, cw0, cw1, cw2, a0, a1, a2);
      #pragma unroll
      for (int i = 0; i < 4; i++) {
        float hr = a0[i] + b_r, hz = a1[i] + b_z, hn = a2[i] + b_n;
        float rr = 1.f / (1.f + __expf(-(unpackf(vr[i]) + hr)));
        float zz = 1.f / (1.f + __expf(-(unpackf(vz[i]) + hz)));
        float e  = __expf(2.f * (unpackf(vn[i]) + rr * hn));
        float nn = 1.f - 2.f / (e + 1.f);
        float hnew = (1.f - zz) * nn + zz * hold[i];
        hold[i] = hnew;
        unsigned short h_  = f2b(hnew);
        unsigned short lo_ = f2b(hnew - b2f(h_));
        int u = g * 4 + i;
        int pos = (((j >> 3) ^ (u & 7)) << 3) + (j & 7);
        h_hi[u][pos] = h_;
        h_lo[u][pos] = lo_;
        h2x[(size_t)(ub + u) * HD + j] = ((unsigned int)h_ << 16) | lo_;
        if (t == lenr[i] - 1)
          out[(size_t)(ub + u) * HD + j] = hnew;
      }
      __syncthreads();
      if (tid == 0)
        __hip_atomic_store(&bflag[myf], t + 1, __ATOMIC_RELEASE, __HIP_MEMORY_SCOPE_AGENT);
    }
  }
}

extern "C" void kernel_launch(void* const* d_in, const int* in_sizes, int n_in,
                              void* d_out, int out_size, void* d_ws, size_t ws_size,
                              hipStream_t stream) {
  const float* prob  = (const float*)d_in[0];
  const int*   seq   = (const int*)d_in[1];
  // d_in[2] = uid (unused by the reference output)
  const float* table = (const float*)d_in[3];
  const float* wih   = (const float*)d_in[4];
  const float* whh   = (const float*)d_in[5];
  const float* bih   = (const float*)d_in[6];
  const float* bhh   = (const float*)d_in[7];
  float* out = (float*)d_out;

  char* ws = (char*)d_ws;
  float* gi            = (float*)ws;                          // 48 MB: gi1, then gi2 overlay
  unsigned short* xbhi = (unsigned short*)(ws + 50331648);    // 8 MB
  unsigned short* xblo = (unsigned short*)(ws + 58720256);    // 8 MB
  unsigned int* h1pk   = (unsigned int*)xbhi;  // overlay: xb dead after gemm1 (16 MiB)
  char* wsw = ws + 67108864;
  const size_t WSZ = 393216;                                  // 768*256*2 B
  unsigned short* wih1hi = (unsigned short*)(wsw + 0 * WSZ);
  unsigned short* wih1lo = (unsigned short*)(wsw + 1 * WSZ);
  unsigned short* wih2hi = (unsigned short*)(wsw + 2 * WSZ);
  unsigned short* wih2lo = (unsigned short*)(wsw + 3 * WSZ);
  unsigned short* whh1hi = (unsigned short*)(wsw + 4 * WSZ);
  unsigned short* whh1lo = (unsigned short*)(wsw + 5 * WSZ);
  unsigned short* whh2hi = (unsigned short*)(wsw + 6 * WSZ);
  unsigned short* whh2lo = (unsigned short*)(wsw + 7 * WSZ);
  int* order   = (int*)(wsw + 8 * WSZ);
  int* lengths = order + KU * NBASK;
  int* flags   = lengths + KU;
  unsigned int* h2x = (unsigned int*)wih1hi;   // overlay: wih1 dead after gemm1 (256 KB < 384 KB)

  k_zero<<<1, 128, 0, stream>>>(flags);
  k_convert<<<dim3(192, 4), 1024, 0, stream>>>(wih, whh,
      wih1hi, wih1lo, wih2hi, wih2lo, whh1hi, whh1lo, whh2hi, whh2lo);
  k_order<<<dim3(KU), 64, 0, stream>>>(prob, seq, order, lengths);
  k_basket<<<dim3(NBASK, KU), 256, 0, stream>>>(prob, seq, table, order, xbhi, xblo);
  // gi1 = x @ wih1^T + bih1  (consumes xb and wih1; those regions then recycle)
  k_gemm3<<<dim3(12, 256), 256, 0, stream>>>(xbhi, xblo, wih1hi, wih1lo, bih, gi);
  // j-split pipelined recur1 -> gi2 -> recur2 (96 blocks, 3 roles x 16 groups x 2 halves)
  k_pipe<<<dim3(96), 512, 0, stream>>>(
      whh1hi, whh1lo, wih2hi, wih2lo, whh2hi, whh2lo,
      gi, h1pk, h2x, bhh, bih + G3, bhh + G3, lengths, out, flags);
}

// Round 11
// 717.137 us; speedup vs baseline: 1.0386x; 1.0386x over previous
//
#include <hip/hip_runtime.h>
#include <cstdint>

#define KU 256
#define NBASK 64
#define MBS 20
#define BITEMS 1280
#define HD 256
#define G3 768
#define TT 64

typedef short v8s __attribute__((ext_vector_type(8)));
typedef float v4f __attribute__((ext_vector_type(4)));
typedef unsigned short v4us __attribute__((ext_vector_type(4)));
typedef unsigned int v4u __attribute__((ext_vector_type(4)));

__device__ __forceinline__ unsigned short f2b(float f){
  uint32_t u = __float_as_uint(f);
  u += 0x7FFFu + ((u >> 16) & 1u);
  return (unsigned short)(u >> 16);
}
__device__ __forceinline__ float b2f(unsigned short s){
  return __uint_as_float(((uint32_t)s) << 16);
}
__device__ __forceinline__ unsigned int packf(float x){
  unsigned short hi = f2b(x);
  unsigned short lo = f2b(x - b2f(hi));
  return ((unsigned int)hi << 16) | lo;
}
__device__ __forceinline__ float unpackf(unsigned int v){
  return b2f((unsigned short)(v >> 16)) + b2f((unsigned short)(v & 0xffffu));
}
// acquire wait (r9 semantics, correctness-proven)
__device__ __forceinline__ void waitflag(int* f, int v){
  while (__hip_atomic_load(f, __ATOMIC_ACQUIRE, __HIP_MEMORY_SCOPE_AGENT) < v)
    __builtin_amdgcn_s_sleep(2);
}

// ---------------- weight conversion: fp32 -> bf16 hi + residual lo ---------
__global__ __launch_bounds__(1024) void k_convert(
    const float* __restrict__ wih, const float* __restrict__ whh,
    unsigned short* __restrict__ wih1hi, unsigned short* __restrict__ wih1lo,
    unsigned short* __restrict__ wih2hi, unsigned short* __restrict__ wih2lo,
    unsigned short* __restrict__ whh1hi, unsigned short* __restrict__ whh1lo,
    unsigned short* __restrict__ whh2hi, unsigned short* __restrict__ whh2lo)
{
  int idx = blockIdx.x * 1024 + threadIdx.x;     // 0..196607
  int which = blockIdx.y;
  float v;
  if (which == 0)      v = wih[idx];
  else if (which == 1) v = wih[196608 + idx];
  else if (which == 2) v = whh[idx];
  else                 v = whh[196608 + idx];
  unsigned short hi = f2b(v);
  unsigned short lo = f2b(v - b2f(hi));
  if (which == 0)      { wih1hi[idx] = hi; wih1lo[idx] = lo; }
  else if (which == 1) { wih2hi[idx] = hi; wih2lo[idx] = lo; }
  else if (which == 2) { whh1hi[idx] = hi; whh1lo[idx] = lo; }
  else                 { whh2hi[idx] = hi; whh2lo[idx] = lo; }
}

// ---------------- flag init ------------------------------------------------
__global__ void k_zero(int* flags){
  if (threadIdx.x < 96) flags[threadIdx.x] = 0;
}

// ---------------- per-user basket ordering (stable: valid first) -----------
__global__ __launch_bounds__(64) void k_order(
    const float* __restrict__ prob, const int* __restrict__ seq,
    int* __restrict__ order, int* __restrict__ lengths)
{
  int k = blockIdx.x, j = threadIdx.x;           // j = basket
  int base = k * BITEMS + j * MBS;
  float mx = 0.f;
  #pragma unroll
  for (int m = 0; m < MBS; m++) {
    int it = seq[base + m];
    float p = (it >= 0) ? prob[base + m] : 0.f;
    mx = fmaxf(mx, p);
  }
  bool valid = mx > 0.f;
  unsigned long long bal = __ballot(valid);
  int len = __popcll(bal);
  unsigned long long below = bal & ((1ull << j) - 1ull);
  int pos = valid ? __popcll(below) : (len + (j - __popcll(below)));
  order[k * NBASK + j] = pos;
  if (j == 0) lengths[k] = (len > 0) ? len : 1;
}

// ---------------- basket pooling -> ordered x (bf16 hi+lo) -----------------
__global__ __launch_bounds__(256) void k_basket(
    const float* __restrict__ prob, const int* __restrict__ seq,
    const float* __restrict__ table, const int* __restrict__ order,
    unsigned short* __restrict__ xbhi, unsigned short* __restrict__ xblo)
{
  int j = blockIdx.x, k = blockIdx.y;
  int h = threadIdx.x;
  int base = k * BITEMS + j * MBS;
  float acc = 0.f, sp = 0.f;
  #pragma unroll
  for (int m = 0; m < MBS; m++) {
    int it = seq[base + m];
    if (it >= 0) {
      float p = prob[base + m];
      sp += p;
      acc += p * table[(size_t)(it + 1) * HD + h];
    }
  }
  float val = acc / (sp + 1e-10f);
  int dest = order[k * NBASK + j];
  unsigned short hi = f2b(val);
  size_t o = ((size_t)k * NBASK + dest) * HD + h;
  xbhi[o] = hi;
  xblo[o] = f2b(val - b2f(hi));
}

// ---------------- 3-product split-bf16 GEMM: Y = X @ W^T + bias ------------
__global__ __launch_bounds__(256) void k_gemm3(
    const unsigned short* __restrict__ Xhi, const unsigned short* __restrict__ Xlo,
    const unsigned short* __restrict__ Whi, const unsigned short* __restrict__ Wlo,
    const float* __restrict__ bias, float* __restrict__ Y)
{
  int nblk = blockIdx.x;              // 0..11
  int mblk = blockIdx.y;              // 0..255
  int wv = threadIdx.x >> 6;
  int l = threadIdx.x & 63;
  int r = l & 15, g = l >> 4;
  int mbase = mblk * 64 + wv * 16;
  int nbase = nblk * 64;
  v4f acc[4];
  #pragma unroll
  for (int c = 0; c < 4; c++) {
    float bn = bias[nbase + c * 16 + r];
    acc[c] = (v4f){bn, bn, bn, bn};
  }
  const unsigned short* xh = Xhi + (size_t)(mbase + r) * HD;
  const unsigned short* xl = Xlo + (size_t)(mbase + r) * HD;
  #pragma unroll
  for (int k0 = 0; k0 < HD; k0 += 32) {
    v8s ahi = *(const v8s*)(xh + k0 + g * 8);
    v8s alo = *(const v8s*)(xl + k0 + g * 8);
    #pragma unroll
    for (int c = 0; c < 4; c++) {
      size_t wo = (size_t)(nbase + c * 16 + r) * HD + k0 + g * 8;
      v8s bhi = *(const v8s*)(Whi + wo);
      v8s blo = *(const v8s*)(Wlo + wo);
      acc[c] = __builtin_amdgcn_mfma_f32_16x16x32_bf16(ahi, bhi, acc[c], 0, 0, 0);
      acc[c] = __builtin_amdgcn_mfma_f32_16x16x32_bf16(alo, bhi, acc[c], 0, 0, 0);
      acc[c] = __builtin_amdgcn_mfma_f32_16x16x32_bf16(ahi, blo, acc[c], 0, 0, 0);
    }
  }
  #pragma unroll
  for (int c = 0; c < 4; c++) {
    int n = nbase + c * 16 + r;
    int mrow = mbase + g * 4;
    #pragma unroll
    for (int i = 0; i < 4; i++)
      Y[(size_t)(mrow + i) * G3 + n] = acc[c][i];
  }
}

// ---------------- full-step weight prefetch (24 loads upfront, 96 VGPR) ----
// cw arrays indexed by loop var (compile-time) -> registers, not scratch.
__device__ __forceinline__ void wload_all(
    const unsigned short* __restrict__ w0, const unsigned short* __restrict__ w1,
    const unsigned short* __restrict__ w2, int half4,
    v8s (&cw0)[8], v8s (&cw1)[8], v8s (&cw2)[8])
{
  #pragma unroll
  for (int kk = 0; kk < 8; kk++) {
    int p = (half4 + kk) & 7;
    cw0[kk] = *(const v8s*)(w0 + p * 32);
    cw1[kk] = *(const v8s*)(w1 + p * 32);
    cw2[kk] = *(const v8s*)(w2 + p * 32);
  }
}
// MFMA over k-slices [K0,KN): slice index p = (half4+kk)&7, so kk<4 touches
// the block's OWN h-half (fresh in local LDS) and kk>=4 the sibling half.
template<int K0, int KN>
__device__ __forceinline__ void mfma_run(
    const unsigned short (*h_hi)[256], const unsigned short (*h_lo)[256],
    const unsigned short* __restrict__ nlo_s, int r, int g, int jloc, int half4,
    const v8s (&cw0)[8], const v8s (&cw1)[8], const v8s (&cw2)[8],
    v4f& a0, v4f& a1, v4f& a2)
{
  #pragma unroll
  for (int kk = K0; kk < KN; kk++) {
    int p = (half4 + kk) & 7;
    int slotA = ((p * 4 + g) ^ (r & 7)) * 8;
    v8s ahi = *(const v8s*)&h_hi[r][slotA];
    v8s alo = *(const v8s*)&h_lo[r][slotA];
    v8s nl  = *(const v8s*)&nlo_s[jloc * 256 + slotA];
    a0 = __builtin_amdgcn_mfma_f32_16x16x32_bf16(ahi, cw0[kk], a0, 0, 0, 0);
    a0 = __builtin_amdgcn_mfma_f32_16x16x32_bf16(alo, cw0[kk], a0, 0, 0, 0);
    a1 = __builtin_amdgcn_mfma_f32_16x16x32_bf16(ahi, cw1[kk], a1, 0, 0, 0);
    a1 = __builtin_amdgcn_mfma_f32_16x16x32_bf16(alo, cw1[kk], a1, 0, 0, 0);
    a2 = __builtin_amdgcn_mfma_f32_16x16x32_bf16(ahi, cw2[kk], a2, 0, 0, 0);
    a2 = __builtin_amdgcn_mfma_f32_16x16x32_bf16(alo, cw2[kk], a2, 0, 0, 0);
    a2 = __builtin_amdgcn_mfma_f32_16x16x32_bf16(ahi, nl, a2, 0, 0, 0);
  }
}

// ---------------- j-split 3-stage pipelined GRU (96 blocks x 512) ----------
// Topology and sync = round 9 (acquire waits; proven). New: full-step weight
// prefetch (24 in-flight loads vs 9) + gi loads issued AFTER all weight loads
// (in-order retirement -> weight waits never block on slow gi) + 256-VGPR
// budget via amdgpu_waves_per_eu(2,2) (512-thr block = 2 waves/SIMD).
__global__ __launch_bounds__(512) __attribute__((amdgpu_waves_per_eu(2, 2)))
void k_pipe(
    const unsigned short* __restrict__ whh1hi, const unsigned short* __restrict__ whh1lo,
    const unsigned short* __restrict__ wih2hi, const unsigned short* __restrict__ wih2lo,
    const unsigned short* __restrict__ whh2hi, const unsigned short* __restrict__ whh2lo,
    float* __restrict__ gi, unsigned int* __restrict__ h1pk, unsigned int* __restrict__ h2x,
    const float* __restrict__ bhh1, const float* __restrict__ bih2,
    const float* __restrict__ bhh2,
    const int* __restrict__ lengths, float* __restrict__ out, int* flags)
{
  __shared__ unsigned short h_hi[16][256], h_lo[16][256];  // 16 KB
  __shared__ unsigned short nlo_s[32768];                  // 64 KB
  int tid = threadIdx.x;
  int l = tid & 63, r = l & 15, g = l >> 4;
  int swv = __builtin_amdgcn_readfirstlane(tid >> 6);
  int bx = blockIdx.x;
  int role = bx >> 5, sub = bx & 31, half = sub >> 4, b = sub & 15;
  int half4 = half * 4;
  int ub = b * 16;
  int jloc = swv * 16 + r, j = half * 128 + jloc;
  int* aflag = flags, *gflag = flags + 32, *bflag = flags + 64;
  int myf = sub, sibf = sub ^ 16;

  const unsigned short* whi_g = (role == 0) ? whh1hi : (role == 1) ? wih2hi : whh2hi;
  const unsigned short* wlo_g = (role == 0) ? whh1lo : (role == 1) ? wih2lo : whh2lo;
  const float* bb_ = (role == 0) ? bhh1 : (role == 1) ? bih2 : bhh2;

  for (int idx = tid; idx < 4096; idx += 512) {
    ((unsigned short*)h_hi)[idx] = 0;
    ((unsigned short*)h_lo)[idx] = 0;
  }
  // stage this block's n-gate lo rows (its j-half), MFMA-read swizzled
  const unsigned short* wlo_n = wlo_g + 2 * 65536 + half * 128 * 256;
  for (int idx = tid; idx < 32768; idx += 512) {
    int row = idx >> 8, col = idx & 255;
    int slot = (col >> 3) ^ (row & 7);
    nlo_s[row * 256 + slot * 8 + (col & 7)] = wlo_n[idx];
  }
  const unsigned short* w0 = whi_g + (size_t)j * 256 + g * 8;
  const unsigned short* w1 = w0 + 65536;
  const unsigned short* w2 = w0 + 131072;
  float b_r = bb_[j], b_z = bb_[256 + j], b_n = bb_[512 + j];
  int sibbase = (1 - half) * 128;
  int xu = tid >> 5;                           // exchange helper coords
  __syncthreads();

  if (role == 0) {
    // ===== stage A: layer-1 recurrence (j-half) =====
    float hold[4] = {0.f, 0.f, 0.f, 0.f};
    const float* gp[4];
    unsigned int* hq[4];
    #pragma unroll
    for (int i = 0; i < 4; i++) {
      gp[i] = gi + (size_t)(ub + g * 4 + i) * TT * G3 + j;
      hq[i] = h1pk + (size_t)(ub + g * 4 + i) * TT * HD + j;
    }
    for (int t = 0; t < TT; t++) {
      v8s cw0[8], cw1[8], cw2[8];
      wload_all(w0, w1, w2, half4, cw0, cw1, cw2);   // 24 loads first
      float gir[4], giz[4], gin[4];
      #pragma unroll
      for (int i = 0; i < 4; i++) {                  // 12 gi loads AFTER weights
        gir[i] = gp[i][0]; giz[i] = gp[i][256]; gin[i] = gp[i][512];
        gp[i] += G3;
      }
      v4f a0 = {0.f,0.f,0.f,0.f}, a1 = {0.f,0.f,0.f,0.f}, a2 = {0.f,0.f,0.f,0.f};
      mfma_run<0,4>(h_hi, h_lo, nlo_s, r, g, jloc, half4, cw0, cw1, cw2, a0, a1, a2);
      if (t > 0 && tid == 0) waitflag(&aflag[sibf], t);
      __syncthreads();
      if (t > 0) {
        int sj = sibbase + (tid & 31) * 4;
        v4u pk = *(const v4u*)&h1pk[((size_t)(ub + xu) * TT + (t - 1)) * HD + sj];
        int pos = (((sj >> 3) ^ (xu & 7)) << 3) + (sj & 7);
        v4us hv, lv;
        #pragma unroll
        for (int i = 0; i < 4; i++) { hv[i] = (unsigned short)(pk[i] >> 16); lv[i] = (unsigned short)(pk[i] & 0xffffu); }
        *(v4us*)&h_hi[xu][pos] = hv;
        *(v4us*)&h_lo[xu][pos] = lv;
      }
      __syncthreads();
      mfma_run<4,8>(h_hi, h_lo, nlo_s, r, g, jloc, half4, cw0, cw1, cw2, a0, a1, a2);
      #pragma unroll
      for (int i = 0; i < 4; i++) {
        float hr = a0[i] + b_r, hz = a1[i] + b_z, hn = a2[i] + b_n;
        float rr = 1.f / (1.f + __expf(-(gir[i] + hr)));
        float zz = 1.f / (1.f + __expf(-(giz[i] + hz)));
        float e  = __expf(2.f * (gin[i] + rr * hn));
        float nn = 1.f - 2.f / (e + 1.f);
        float hnew = (1.f - zz) * nn + zz * hold[i];
        hold[i] = hnew;
        unsigned short h_  = f2b(hnew);
        unsigned short lo_ = f2b(hnew - b2f(h_));
        int u = g * 4 + i;
        int pos = (((j >> 3) ^ (u & 7)) << 3) + (j & 7);
        h_hi[u][pos] = h_;
        h_lo[u][pos] = lo_;
        hq[i][0] = ((unsigned int)h_ << 16) | lo_;
        hq[i] += HD;
      }
      __syncthreads();
      if (tid == 0) {
        __threadfence();
        __hip_atomic_store(&aflag[myf], t + 1, __ATOMIC_RELEASE, __HIP_MEMORY_SCOPE_AGENT);
      }
    }
  } else if (role == 1) {
    // ===== stage G: gi2(t) = h1(t) @ wih2^T + bih2 (j-half rows) =====
    unsigned int* gi_u = (unsigned int*)gi;
    for (int t = 0; t < TT; t++) {
      v8s cw0[8], cw1[8], cw2[8];
      wload_all(w0, w1, w2, half4, cw0, cw1, cw2);   // hidden under flag wait
      if (tid == 0) { waitflag(&aflag[b], t + 1); waitflag(&aflag[16 + b], t + 1); }
      __syncthreads();
      {
        int c0 = (tid & 31) * 8;
        const unsigned int* src = &h1pk[((size_t)(ub + xu) * TT + t) * HD + c0];
        #pragma unroll
        for (int hf = 0; hf < 2; hf++) {
          v4u pk = *(const v4u*)(src + hf * 4);
          int sj = c0 + hf * 4;
          int pos = (((sj >> 3) ^ (xu & 7)) << 3) + (sj & 7);
          v4us hv, lv;
          #pragma unroll
          for (int i = 0; i < 4; i++) { hv[i] = (unsigned short)(pk[i] >> 16); lv[i] = (unsigned short)(pk[i] & 0xffffu); }
          *(v4us*)&h_hi[xu][pos] = hv;
          *(v4us*)&h_lo[xu][pos] = lv;
        }
      }
      __syncthreads();
      v4f a0 = {b_r, b_r, b_r, b_r}, a1 = {b_z, b_z, b_z, b_z}, a2 = {b_n, b_n, b_n, b_n};
      mfma_run<0,8>(h_hi, h_lo, nlo_s, r, g, jloc, half4, cw0, cw1, cw2, a0, a1, a2);
      #pragma unroll
      for (int i = 0; i < 4; i++) {
        size_t base = ((size_t)(ub + g * 4 + i) * TT + t) * G3;
        gi_u[base + j]       = packf(a0[i]);
        gi_u[base + 256 + j] = packf(a1[i]);
        gi_u[base + 512 + j] = packf(a2[i]);
      }
      __syncthreads();
      if (tid == 0) {
        __threadfence();
        __hip_atomic_store(&gflag[myf], t + 1, __ATOMIC_RELEASE, __HIP_MEMORY_SCOPE_AGENT);
      }
    }
  } else {
    // ===== stage B: layer-2 recurrence (j-half) =====
    float hold[4] = {0.f, 0.f, 0.f, 0.f};
    const unsigned int* gq[4];
    int lenr[4];
    #pragma unroll
    for (int i = 0; i < 4; i++) {
      gq[i] = (const unsigned int*)gi + (size_t)(ub + g * 4 + i) * TT * G3 + j;
      lenr[i] = lengths[ub + g * 4 + i];
    }
    for (int t = 0; t < TT; t++) {
      v8s cw0[8], cw1[8], cw2[8];
      wload_all(w0, w1, w2, half4, cw0, cw1, cw2);
      v4f a0 = {0.f,0.f,0.f,0.f}, a1 = {0.f,0.f,0.f,0.f}, a2 = {0.f,0.f,0.f,0.f};
      mfma_run<0,4>(h_hi, h_lo, nlo_s, r, g, jloc, half4, cw0, cw1, cw2, a0, a1, a2);
      if (tid == 0) {
        waitflag(&gflag[myf], t + 1);
        if (t > 0) waitflag(&bflag[sibf], t);
      }
      __syncthreads();
      if (t > 0) {
        int sj = sibbase + (tid & 31) * 4;
        v4u pk = *(const v4u*)&h2x[(size_t)(ub + xu) * HD + sj];
        int pos = (((sj >> 3) ^ (xu & 7)) << 3) + (sj & 7);
        v4us hv, lv;
        #pragma unroll
        for (int i = 0; i < 4; i++) { hv[i] = (unsigned short)(pk[i] >> 16); lv[i] = (unsigned short)(pk[i] & 0xffffu); }
        *(v4us*)&h_hi[xu][pos] = hv;
        *(v4us*)&h_lo[xu][pos] = lv;
      }
      unsigned int vr[4], vz[4], vn[4];
      #pragma unroll
      for (int i = 0; i < 4; i++) {
        vr[i] = gq[i][0]; vz[i] = gq[i][256]; vn[i] = gq[i][512];
        gq[i] += G3;
      }
      __syncthreads();
      mfma_run<4,8>(h_hi, h_lo, nlo_s, r, g, jloc, half4, cw0, cw1, cw2, a0, a1, a2);
      #pragma unroll
      for (int i = 0; i < 4; i++) {
        float hr = a0[i] + b_r, hz = a1[i] + b_z, hn = a2[i] + b_n;
        float rr = 1.f / (1.f + __expf(-(unpackf(vr[i]) + hr)));
        float zz = 1.f / (1.f + __expf(-(unpackf(vz[i]) + hz)));
        float e  = __expf(2.f * (unpackf(vn[i]) + rr * hn));
        float nn = 1.f - 2.f / (e + 1.f);
        float hnew = (1.f - zz) * nn + zz * hold[i];
        hold[i] = hnew;
        unsigned short h_  = f2b(hnew);
        unsigned short lo_ = f2b(hnew - b2f(h_));
        int u = g * 4 + i;
        int pos = (((j >> 3) ^ (u & 7)) << 3) + (j & 7);
        h_hi[u][pos] = h_;
        h_lo[u][pos] = lo_;
        h2x[(size_t)(ub + u) * HD + j] = ((unsigned int)h_ << 16) | lo_;
        if (t == lenr[i] - 1)
          out[(size_t)(ub + u) * HD + j] = hnew;
      }
      __syncthreads();
      if (tid == 0) {
        __threadfence();
        __hip_atomic_store(&bflag[myf], t + 1, __ATOMIC_RELEASE, __HIP_MEMORY_SCOPE_AGENT);
      }
    }
  }
}

extern "C" void kernel_launch(void* const* d_in, const int* in_sizes, int n_in,
                              void* d_out, int out_size, void* d_ws, size_t ws_size,
                              hipStream_t stream) {
  const float* prob  = (const float*)d_in[0];
  const int*   seq   = (const int*)d_in[1];
  // d_in[2] = uid (unused by the reference output)
  const float* table = (const float*)d_in[3];
  const float* wih   = (const float*)d_in[4];
  const float* whh   = (const float*)d_in[5];
  const float* bih   = (const float*)d_in[6];
  const float* bhh   = (const float*)d_in[7];
  float* out = (float*)d_out;

  char* ws = (char*)d_ws;
  float* gi            = (float*)ws;                          // 48 MB: gi1, then gi2 overlay
  unsigned short* xbhi = (unsigned short*)(ws + 50331648);    // 8 MB
  unsigned short* xblo = (unsigned short*)(ws + 58720256);    // 8 MB
  unsigned int* h1pk   = (unsigned int*)xbhi;  // overlay: xb dead after gemm1 (16 MiB)
  char* wsw = ws + 67108864;
  const size_t WSZ = 393216;                                  // 768*256*2 B
  unsigned short* wih1hi = (unsigned short*)(wsw + 0 * WSZ);
  unsigned short* wih1lo = (unsigned short*)(wsw + 1 * WSZ);
  unsigned short* wih2hi = (unsigned short*)(wsw + 2 * WSZ);
  unsigned short* wih2lo = (unsigned short*)(wsw + 3 * WSZ);
  unsigned short* whh1hi = (unsigned short*)(wsw + 4 * WSZ);
  unsigned short* whh1lo = (unsigned short*)(wsw + 5 * WSZ);
  unsigned short* whh2hi = (unsigned short*)(wsw + 6 * WSZ);
  unsigned short* whh2lo = (unsigned short*)(wsw + 7 * WSZ);
  int* order   = (int*)(wsw + 8 * WSZ);
  int* lengths = order + KU * NBASK;
  int* flags   = lengths + KU;
  unsigned int* h2x = (unsigned int*)wih1hi;   // overlay: wih1 dead after gemm1

  k_zero<<<1, 128, 0, stream>>>(flags);
  k_convert<<<dim3(192, 4), 1024, 0, stream>>>(wih, whh,
      wih1hi, wih1lo, wih2hi, wih2lo, whh1hi, whh1lo, whh2hi, whh2lo);
  k_order<<<dim3(KU), 64, 0, stream>>>(prob, seq, order, lengths);
  k_basket<<<dim3(NBASK, KU), 256, 0, stream>>>(prob, seq, table, order, xbhi, xblo);
  // gi1 = x @ wih1^T + bih1  (consumes xb and wih1; those regions then recycle)
  k_gemm3<<<dim3(12, 256), 256, 0, stream>>>(xbhi, xblo, wih1hi, wih1lo, bih, gi);
  // j-split pipelined recur1 -> gi2 -> recur2 (96 blocks, 3 roles x 16 groups x 2 halves)
  k_pipe<<<dim3(96), 512, 0, stream>>>(
      whh1hi, whh1lo, wih2hi, wih2lo, whh2hi, whh2lo,
      gi, h1pk, h2x, bhh, bih + G3, bhh + G3, lengths, out, flags);
}